// Round 4
// baseline (769.435 us; speedup 1.0000x reference)
//
#include <hip/hip_runtime.h>
#include <math.h>

#define HIDDEN 96
#define NNODES 50000
#define NEDGES 800000
#define INDIM  256
#define RS 0.07216878364870323f   // 1/sqrt(2*HIDDEN)

// Native clang vector for nontemporal builtins (HIP_vector_type is rejected).
typedef float f4raw __attribute__((ext_vector_type(4)));

__device__ __forceinline__ void nt_store4(float* p, float4 v) {
    f4raw r;
    r.x = v.x; r.y = v.y; r.z = v.z; r.w = v.w;
    __builtin_nontemporal_store(r, (f4raw*)p);
}

// fast tanh: clamp + v_exp_f32 + v_rcp_f32 (~7 instrs vs ~20+ for libm).
// Clamp keeps exp finite; accuracy ~1e-6 abs, far under the bf16-ulp compare.
__device__ __forceinline__ float fast_tanh(float x) {
    x = fminf(15.0f, fmaxf(-15.0f, x));          // v_med3_f32
    float e = __expf(2.0f * x);                  // v_exp_f32 path
    return (e - 1.0f) * __builtin_amdgcn_rcpf(e + 1.0f);
}

// ---------------------------------------------------------------------------
// Repack W_gate [96][192] into V [192][96]: V[j][k] = Wg[j][k]*RS (j<96),
// V[96+j][k] = Wg[j][96+k]*RS; bias2 = [b_gate*RS, 0].
// ---------------------------------------------------------------------------
__global__ void repack_kernel(const float* __restrict__ Wg, const float* __restrict__ bg,
                              float* __restrict__ V, float* __restrict__ bias2) {
    int idx = blockIdx.x * 256 + threadIdx.x;
    if (idx < 192 * 96) {
        int j = idx / 96, k = idx % 96;
        float v = (j < 96) ? Wg[j * 192 + k] : Wg[(j - 96) * 192 + 96 + k];
        V[idx] = v * RS;
    }
    if (idx < 192) bias2[idx] = (idx < 96) ? bg[idx] * RS : 0.0f;
}

// ---------------------------------------------------------------------------
// C[M][ldc] = A[M][K] @ B[NB][K]^T + bias.  BM=128, BN=96, BK=32, 256 thr,
// 8x6 micro-tile. Rows te+16i / cols tc+16j so the wave's A-side LDS reads
// hit disjoint bank quads (row stride 36 floats -> +4 banks per te lane);
// B-side is the unavoidable 2-way (16 lanes x 16B = 256B > 128B LDS width).
// ---------------------------------------------------------------------------
__global__ __launch_bounds__(256) void gemm_nt_bias(
    const float* __restrict__ A, const float* __restrict__ B,
    const float* __restrict__ bias, float* __restrict__ C,
    int M, int K, int ldc) {
    __shared__ float As[128][36];
    __shared__ float Bs[96][36];
    const int tid = threadIdx.x;
    const int m0 = blockIdx.x * 128;
    const int n0 = blockIdx.y * 96;
    const int te = tid >> 4;       // 0..15 -> rows te, te+16, ..., te+112
    const int tc = tid & 15;       // 0..15 -> cols tc, tc+16, ..., tc+80
    const int ra = tid >> 3;       // 0..31 load row
    const int ka = (tid & 7) * 4;  // k offset (float4)

    float acc[8][6];
#pragma unroll
    for (int i = 0; i < 8; i++)
#pragma unroll
        for (int j = 0; j < 6; j++) acc[i][j] = 0.0f;

    for (int k0 = 0; k0 < K; k0 += 32) {
#pragma unroll
        for (int r = 0; r < 4; r++) {
            int row = m0 + ra + r * 32;
            float4 v = make_float4(0, 0, 0, 0);
            if (row < M) v = *(const float4*)&A[(size_t)row * K + k0 + ka];
            *(float4*)&As[ra + r * 32][ka] = v;
        }
#pragma unroll
        for (int r = 0; r < 3; r++) {
            int row = n0 + ra + r * 32;   // always valid by grid construction
            float4 v = *(const float4*)&B[(size_t)row * K + k0 + ka];
            *(float4*)&Bs[ra + r * 32][ka] = v;
        }
        __syncthreads();
#pragma unroll
        for (int k4 = 0; k4 < 32; k4 += 4) {
            float4 af[8], bf[6];
#pragma unroll
            for (int i = 0; i < 8; i++) af[i] = *(float4*)&As[te + 16 * i][k4];
#pragma unroll
            for (int j = 0; j < 6; j++) bf[j] = *(float4*)&Bs[tc + 16 * j][k4];
#pragma unroll
            for (int i = 0; i < 8; i++)
#pragma unroll
                for (int j = 0; j < 6; j++)
                    acc[i][j] += af[i].x * bf[j].x + af[i].y * bf[j].y +
                                 af[i].z * bf[j].z + af[i].w * bf[j].w;
        }
        __syncthreads();
    }
#pragma unroll
    for (int i = 0; i < 8; i++) {
        int row = m0 + te + 16 * i;
        if (row < M) {
#pragma unroll
            for (int j = 0; j < 6; j++) {
                int col = n0 + tc + 16 * j;
                C[(size_t)row * ldc + col] = acc[i][j] + bias[col];
            }
        }
    }
}

// ---------------------------------------------------------------------------
// CSR build: histogram of dst -> block scan -> scatter packed edge records.
// ---------------------------------------------------------------------------
__global__ void hist_kernel(const int* __restrict__ dst, int* __restrict__ counts) {
    int i = blockIdx.x * 256 + threadIdx.x;
    if (i < NEDGES) atomicAdd(&counts[dst[i]], 1);
}

__global__ __launch_bounds__(512) void scan1_kernel(const int* __restrict__ counts,
                                                    int* __restrict__ offsets,
                                                    int* __restrict__ btot) {
    __shared__ int sh[512];
    int tid = threadIdx.x;
    int i = blockIdx.x * 512 + tid;
    int v = (i < NNODES) ? counts[i] : 0;
    sh[tid] = v;
    __syncthreads();
    for (int off = 1; off < 512; off <<= 1) {
        int tmp = 0;
        if (tid >= off) tmp = sh[tid - off];
        __syncthreads();
        if (tid >= off) sh[tid] += tmp;
        __syncthreads();
    }
    if (i < NNODES) offsets[i] = sh[tid] - v;     // exclusive within block
    if (tid == 511) btot[blockIdx.x] = sh[511];
}

__global__ __launch_bounds__(128) void scan2_kernel(int* __restrict__ btot, int nb) {
    __shared__ int sh[128];
    int tid = threadIdx.x;
    int v = (tid < nb) ? btot[tid] : 0;
    sh[tid] = v;
    __syncthreads();
    for (int off = 1; off < 128; off <<= 1) {
        int tmp = 0;
        if (tid >= off) tmp = sh[tid - off];
        __syncthreads();
        if (tid >= off) sh[tid] += tmp;
        __syncthreads();
    }
    if (tid < nb) btot[tid] = sh[tid] - v;        // exclusive over blocks
}

// Adds block prefix; also initializes cursor = offsets so scatter's atomicAdd
// yields absolute positions (no offsets gather in scatter).
__global__ __launch_bounds__(512) void scan3_kernel(int* __restrict__ offsets,
                                                    int* __restrict__ cursor,
                                                    const int* __restrict__ btot) {
    int i = blockIdx.x * 512 + threadIdx.x;
    if (i < NNODES) {
        int v = offsets[i] + btot[blockIdx.x];
        offsets[i] = v;
        cursor[i] = v;
    }
    if (i == 0) offsets[NNODES] = NEDGES;
}

// epack[pos] = {edge_id, src, bits(d[src]), 0} — one 16B record per edge.
__global__ void scatter_kernel(const int* __restrict__ src, const int* __restrict__ dst,
                               const float* __restrict__ dvec,
                               int* __restrict__ cursor, int4* __restrict__ epack) {
    int e = blockIdx.x * 256 + threadIdx.x;
    if (e < NEDGES) {
        int t = dst[e];
        int s = src[e];
        int pos = atomicAdd(&cursor[t], 1);
        epack[pos] = make_int4(e, s, __float_as_int(dvec[s]), 0);
    }
}

// ---------------------------------------------------------------------------
// Aggregation: 24-lane group per dst node (float4 chunk per lane). Edge loop
// unrolled 2-wide (independent gather chains overlap). z in registers, no
// atomics. Classifier + log_softmax fused via LDS reduction.
// ---------------------------------------------------------------------------
#define GPB 16   // node groups per block (384 threads = 6 waves)
#define TPG 24   // threads per group (24 x float4 = 96 cols)
__global__ __launch_bounds__(GPB * TPG) void agg_kernel(
    const float* __restrict__ P, const float* __restrict__ h,
    const float* __restrict__ dvec, const int* __restrict__ offsets,
    const int4* __restrict__ epack,
    const float* __restrict__ Wc, const float* __restrict__ bc,
    float* __restrict__ a_out, float* __restrict__ z_out) {
    __shared__ float red0[GPB * TPG];
    __shared__ float red1[GPB * TPG];
    const int t = threadIdx.x;
    const int g = t / TPG;
    const int c = t % TPG;
    const int node = blockIdx.x * GPB + g;
    float s0 = 0.0f, s1 = 0.0f;
    if (node < NNODES) {
        float4 pd = *(const float4*)&P[(size_t)node * 192 + 4 * c];
        float dt = dvec[node];
        int i = offsets[node];
        const int end = offsets[node + 1];
        float4 z4 = make_float4(0, 0, 0, 0);
        for (; i + 2 <= end; i += 2) {
            int4 p0 = epack[i];
            int4 p1 = epack[i + 1];
            float4 ps0 = *(const float4*)&P[(size_t)p0.y * 192 + 96 + 4 * c];
            float4 hs0 = *(const float4*)&h[(size_t)p0.y * 96 + 4 * c];
            float4 ps1 = *(const float4*)&P[(size_t)p1.y * 192 + 96 + 4 * c];
            float4 hs1 = *(const float4*)&h[(size_t)p1.y * 96 + 4 * c];
            float e0 = dt * __int_as_float(p0.z);
            float e1 = dt * __int_as_float(p1.z);
            float4 a0, a1;
            a0.x = fast_tanh(pd.x + ps0.x);
            a0.y = fast_tanh(pd.y + ps0.y);
            a0.z = fast_tanh(pd.z + ps0.z);
            a0.w = fast_tanh(pd.w + ps0.w);
            a1.x = fast_tanh(pd.x + ps1.x);
            a1.y = fast_tanh(pd.y + ps1.y);
            a1.z = fast_tanh(pd.z + ps1.z);
            a1.w = fast_tanh(pd.w + ps1.w);
            nt_store4(&a_out[(size_t)p0.x * 96 + 4 * c], a0);
            nt_store4(&a_out[(size_t)p1.x * 96 + 4 * c], a1);
            z4.x += hs0.x * a0.x * e0 + hs1.x * a1.x * e1;
            z4.y += hs0.y * a0.y * e0 + hs1.y * a1.y * e1;
            z4.z += hs0.z * a0.z * e0 + hs1.z * a1.z * e1;
            z4.w += hs0.w * a0.w * e0 + hs1.w * a1.w * e1;
        }
        if (i < end) {
            int4 p0 = epack[i];
            float4 ps0 = *(const float4*)&P[(size_t)p0.y * 192 + 96 + 4 * c];
            float4 hs0 = *(const float4*)&h[(size_t)p0.y * 96 + 4 * c];
            float e0 = dt * __int_as_float(p0.z);
            float4 a0;
            a0.x = fast_tanh(pd.x + ps0.x);
            a0.y = fast_tanh(pd.y + ps0.y);
            a0.z = fast_tanh(pd.z + ps0.z);
            a0.w = fast_tanh(pd.w + ps0.w);
            nt_store4(&a_out[(size_t)p0.x * 96 + 4 * c], a0);
            z4.x += hs0.x * a0.x * e0;
            z4.y += hs0.y * a0.y * e0;
            z4.z += hs0.z * a0.z * e0;
            z4.w += hs0.w * a0.w * e0;
        }
        float4 w0 = *(const float4*)&Wc[4 * c];
        float4 w1 = *(const float4*)&Wc[96 + 4 * c];
        s0 = z4.x * w0.x + z4.y * w0.y + z4.z * w0.z + z4.w * w0.w;
        s1 = z4.x * w1.x + z4.y * w1.y + z4.z * w1.z + z4.w * w1.w;
    }
    red0[t] = s0;
    red1[t] = s1;
    __syncthreads();
    if (c == 0 && node < NNODES) {
        float a0 = bc[0], a1 = bc[1];
#pragma unroll
        for (int k = 0; k < TPG; k++) { a0 += red0[t + k]; a1 += red1[t + k]; }
        float m = fmaxf(a0, a1);
        float lse = m + logf(expf(a0 - m) + expf(a1 - m));
        z_out[2 * node + 0] = a0 - lse;
        z_out[2 * node + 1] = a1 - lse;
    }
}

extern "C" void kernel_launch(void* const* d_in, const int* in_sizes, int n_in,
                              void* d_out, int out_size, void* d_ws, size_t ws_size,
                              hipStream_t stream) {
    const float* x    = (const float*)d_in[0];
    const float* dvec = (const float*)d_in[1];
    const int*   src  = (const int*)d_in[2];
    const int*   dst  = (const int*)d_in[3];
    const float* W_in = (const float*)d_in[4];
    const float* b_in = (const float*)d_in[5];
    const float* W_g  = (const float*)d_in[6];
    const float* b_g  = (const float*)d_in[7];
    const float* W_c  = (const float*)d_in[8];
    const float* b_c  = (const float*)d_in[9];

    float* z_out = (float*)d_out;                 // [50000*2]
    float* a_out = (float*)d_out + 2 * NNODES;    // [800000*96]

    char* ws = (char*)d_ws;
    float* h       = (float*)(ws);                 // 19,200,000 B
    float* P       = (float*)(ws + 19200000);      // 38,400,000 B
    float* V       = (float*)(ws + 57600000);      // 73,728 B
    float* b2      = (float*)(ws + 57673728);      // 1,024 B (768 used)
    int*   offsets = (int*)  (ws + 57674752);      // 200,064 B (50001 used)
    int*   counts  = (int*)  (ws + 57874816);      // 200,064 B
    int*   cursor  = (int*)  (ws + 58074880);      // 200,064 B
    int*   btot    = (int*)  (ws + 58274944);      // 1,024 B (392 used)
    int4*  epack   = (int4*) (ws + 58275968);      // 12,800,000 B
    // total 71,075,968 B

    (void)hipMemsetAsync(counts, 0, NNODES * sizeof(int), stream);

    repack_kernel<<<dim3((192 * 96 + 255) / 256), 256, 0, stream>>>(W_g, b_g, V, b2);
    // h = x @ W_in.T + b_in   [50000 x 96], K=256
    gemm_nt_bias<<<dim3((NNODES + 127) / 128, 1), 256, 0, stream>>>(x, W_in, b_in, h, NNODES, INDIM, HIDDEN);
    // P = h @ V.T + bias2     [50000 x 192], K=96
    gemm_nt_bias<<<dim3((NNODES + 127) / 128, 2), 256, 0, stream>>>(h, V, b2, P, NNODES, HIDDEN, 192);

    // CSR by dst
    const int NB = (NNODES + 511) / 512;  // 98
    hist_kernel<<<dim3((NEDGES + 255) / 256), 256, 0, stream>>>(dst, counts);
    scan1_kernel<<<dim3(NB), 512, 0, stream>>>(counts, offsets, btot);
    scan2_kernel<<<dim3(1), 128, 0, stream>>>(btot, NB);
    scan3_kernel<<<dim3(NB), 512, 0, stream>>>(offsets, cursor, btot);
    scatter_kernel<<<dim3((NEDGES + 255) / 256), 256, 0, stream>>>(src, dst, dvec, cursor, epack);

    // Edge pass + scatter-free aggregation + fused classifier/log_softmax
    agg_kernel<<<dim3((NNODES + GPB - 1) / GPB), GPB * TPG, 0, stream>>>(
        P, h, dvec, offsets, epack, W_c, b_c, a_out, z_out);
}